// Round 1
// baseline (4146.371 us; speedup 1.0000x reference)
//
#include <hip/hip_runtime.h>

// ---------- helpers ----------

// Order-preserving float -> uint map (monotone increasing).
__device__ __forceinline__ unsigned fmap(float f) {
    unsigned u = __float_as_uint(f);
    return (u & 0x80000000u) ? ~u : (u | 0x80000000u);
}
__device__ __forceinline__ float funmap(unsigned m) {
    unsigned u = (m & 0x80000000u) ? (m & 0x7FFFFFFFu) : ~m;
    return __uint_as_float(u);
}

__device__ __forceinline__ unsigned long long shfl_xor_u64(unsigned long long v, int mask) {
    unsigned lo = (unsigned)(v & 0xFFFFFFFFu);
    unsigned hi = (unsigned)(v >> 32);
    lo = __shfl_xor(lo, mask, 64);
    hi = __shfl_xor(hi, mask, 64);
    return (((unsigned long long)hi) << 32) | lo;
}

// ---------- kernels ----------

// Init reduction buffers (must run every call; ws is not re-poisoned).
__global__ void init_kernel(unsigned long long* packed, unsigned* maxsim,
                            unsigned long long* minall, unsigned long long* minsame,
                            int Q, int B) {
    int i = blockIdx.x * blockDim.x + threadIdx.x;
    if (i < Q) packed[i] = 0ULL;
    if (i < B) { maxsim[i] = 0u; minall[i] = ~0ULL; minsame[i] = ~0ULL; }
}

// One wave per row: rn[row] = 1 / max(||X[row,:256]||, 1e-12)
__global__ void norms_kernel(const float* __restrict__ X, float* __restrict__ rn, int rows) {
    int w = (blockIdx.x * blockDim.x + threadIdx.x) >> 6;
    int lane = threadIdx.x & 63;
    if (w >= rows) return;
    float4 v = *(const float4*)&X[(long)w * 256 + lane * 4];
    float s = v.x * v.x + v.y * v.y + v.z * v.z + v.w * v.w;
    #pragma unroll
    for (int o = 32; o >= 1; o >>= 1) s += __shfl_xor(s, o, 64);
    if (lane == 0) rn[w] = 1.0f / fmaxf(sqrtf(s), 1e-12f);
}

// 128x128 fp32 tile GEMM with fused rowwise max/argmax merge.
__global__ __launch_bounds__(256) void retrieve_gemm(
    const float* __restrict__ A, const float* __restrict__ Bm,
    const float* __restrict__ rq, const float* __restrict__ rm,
    int Q, int M, unsigned long long* __restrict__ packed) {
    __shared__ float As[128][33];
    __shared__ float Bs[128][33];
    const int q0 = blockIdx.x * 128;
    const int m0 = blockIdx.y * 128;
    const int tid = threadIdx.x;
    const int tx = tid & 15, ty = tid >> 4;

    float acc[8][8];
    #pragma unroll
    for (int i = 0; i < 8; ++i)
        #pragma unroll
        for (int j = 0; j < 8; ++j) acc[i][j] = 0.f;

    for (int kc = 0; kc < 256; kc += 32) {
        #pragma unroll
        for (int r = 0; r < 4; ++r) {
            int f = tid + 256 * r;
            int row = f >> 3;
            int kv = (f & 7) << 2;
            int gq = q0 + row;
            float4 av = make_float4(0.f, 0.f, 0.f, 0.f);
            if (gq < Q) av = *(const float4*)&A[(long)gq * 256 + kc + kv];
            As[row][kv + 0] = av.x; As[row][kv + 1] = av.y;
            As[row][kv + 2] = av.z; As[row][kv + 3] = av.w;
            int gm = m0 + row;
            float4 bv = make_float4(0.f, 0.f, 0.f, 0.f);
            if (gm < M) bv = *(const float4*)&Bm[(long)gm * 256 + kc + kv];
            Bs[row][kv + 0] = bv.x; Bs[row][kv + 1] = bv.y;
            Bs[row][kv + 2] = bv.z; Bs[row][kv + 3] = bv.w;
        }
        __syncthreads();
        #pragma unroll
        for (int kk = 0; kk < 32; ++kk) {
            float a[8], b[8];
            #pragma unroll
            for (int i = 0; i < 8; ++i) a[i] = As[ty + 16 * i][kk];
            #pragma unroll
            for (int j = 0; j < 8; ++j) b[j] = Bs[tx + 16 * j][kk];
            #pragma unroll
            for (int i = 0; i < 8; ++i)
                #pragma unroll
                for (int j = 0; j < 8; ++j) acc[i][j] = fmaf(a[i], b[j], acc[i][j]);
        }
        __syncthreads();
    }

    int mi[8]; float rmv[8];
    #pragma unroll
    for (int j = 0; j < 8; ++j) {
        mi[j] = m0 + tx + 16 * j;
        rmv[j] = (mi[j] < M) ? rm[mi[j]] : 0.f;
    }
    #pragma unroll
    for (int i = 0; i < 8; ++i) {
        int q = q0 + ty + 16 * i;
        if (q >= Q) continue;
        float rqv = rq[q];
        unsigned long long best = 0ULL;
        #pragma unroll
        for (int j = 0; j < 8; ++j) {
            if (mi[j] < M) {
                float s = acc[i][j] * rqv * rmv[j];
                // value asc; tie -> larger ~m = smaller m wins (first-index argmax)
                unsigned long long key =
                    (((unsigned long long)fmap(s)) << 32) | (unsigned)(~(unsigned)mi[j]);
                if (key > best) best = key;
            }
        }
        #pragma unroll
        for (int o = 1; o < 16; o <<= 1) {
            unsigned long long other = shfl_xor_u64(best, o);
            if (other > best) best = other;
        }
        if (tx == 0) atomicMax(&packed[q], best);
    }
}

// Update-path GEMM: 128 (B) x 128 memory tile; fused max / argmin-all / argmin-same-class.
__global__ __launch_bounds__(256) void upd_gemm(
    const float* __restrict__ U, const float* __restrict__ Bm,
    const float* __restrict__ ru, const float* __restrict__ rm,
    const int* __restrict__ memvals, const int* __restrict__ lbl,
    int B, int M,
    unsigned* __restrict__ maxsim, unsigned long long* __restrict__ minall,
    unsigned long long* __restrict__ minsame) {
    __shared__ float As[128][33];
    __shared__ float Bs[128][33];
    const int m0 = blockIdx.x * 128;
    const int tid = threadIdx.x;
    const int tx = tid & 15, ty = tid >> 4;

    float acc[8][8];
    #pragma unroll
    for (int i = 0; i < 8; ++i)
        #pragma unroll
        for (int j = 0; j < 8; ++j) acc[i][j] = 0.f;

    for (int kc = 0; kc < 256; kc += 32) {
        #pragma unroll
        for (int r = 0; r < 4; ++r) {
            int f = tid + 256 * r;
            int row = f >> 3;
            int kv = (f & 7) << 2;
            float4 av = make_float4(0.f, 0.f, 0.f, 0.f);
            if (row < B) av = *(const float4*)&U[(long)row * 256 + kc + kv];
            As[row][kv + 0] = av.x; As[row][kv + 1] = av.y;
            As[row][kv + 2] = av.z; As[row][kv + 3] = av.w;
            int gm = m0 + row;
            float4 bv = make_float4(0.f, 0.f, 0.f, 0.f);
            if (gm < M) bv = *(const float4*)&Bm[(long)gm * 256 + kc + kv];
            Bs[row][kv + 0] = bv.x; Bs[row][kv + 1] = bv.y;
            Bs[row][kv + 2] = bv.z; Bs[row][kv + 3] = bv.w;
        }
        __syncthreads();
        #pragma unroll
        for (int kk = 0; kk < 32; ++kk) {
            float a[8], b[8];
            #pragma unroll
            for (int i = 0; i < 8; ++i) a[i] = As[ty + 16 * i][kk];
            #pragma unroll
            for (int j = 0; j < 8; ++j) b[j] = Bs[tx + 16 * j][kk];
            #pragma unroll
            for (int i = 0; i < 8; ++i)
                #pragma unroll
                for (int j = 0; j < 8; ++j) acc[i][j] = fmaf(a[i], b[j], acc[i][j]);
        }
        __syncthreads();
    }

    int mi[8]; float rmv[8]; int mvv[8];
    #pragma unroll
    for (int j = 0; j < 8; ++j) {
        mi[j] = m0 + tx + 16 * j;
        rmv[j] = (mi[j] < M) ? rm[mi[j]] : 0.f;
        mvv[j] = (mi[j] < M) ? memvals[mi[j]] : -1;
    }
    #pragma unroll
    for (int i = 0; i < 8; ++i) {
        int b = ty + 16 * i;
        unsigned bmax = 0u;
        unsigned long long ball = ~0ULL, bsame = ~0ULL;
        float rbv = 0.f; int lb = -2;
        if (b < B) { rbv = ru[b]; lb = lbl[b]; }
        #pragma unroll
        for (int j = 0; j < 8; ++j) {
            if (b < B && mi[j] < M) {
                float s = acc[i][j] * rbv * rmv[j];
                unsigned ms = fmap(s);
                if (ms > bmax) bmax = ms;
                unsigned long long key = (((unsigned long long)ms) << 32) | (unsigned)mi[j];
                if (key < ball) ball = key;
                if (mvv[j] == lb && key < bsame) bsame = key;
            }
        }
        #pragma unroll
        for (int o = 1; o < 16; o <<= 1) {
            unsigned om = __shfl_xor(bmax, o, 64);
            if (om > bmax) bmax = om;
            unsigned long long oa = shfl_xor_u64(ball, o);
            if (oa < ball) ball = oa;
            unsigned long long os = shfl_xor_u64(bsame, o);
            if (os < bsame) bsame = os;
        }
        if (tx == 0 && b < B) {
            atomicMax(&maxsim[b], bmax);
            atomicMin(&minall[b], ball);
            atomicMin(&minsame[b], bsame);
        }
    }
}

__global__ void finish_retrieve(const unsigned long long* __restrict__ packed,
                                const int* __restrict__ memvals,
                                float* __restrict__ out, int Q) {
    int q = blockIdx.x * blockDim.x + threadIdx.x;
    if (q >= Q) return;
    unsigned long long key = packed[q];
    unsigned m = ~((unsigned)(key & 0xFFFFFFFFu));
    float conf = funmap((unsigned)(key >> 32));
    out[q] = (float)memvals[m];
    out[Q + q] = conf;
}

// Resolve update targets with last-write-wins semantics.
__global__ void finish_upd(const unsigned* __restrict__ maxsim,
                           const unsigned long long* __restrict__ minall,
                           const unsigned long long* __restrict__ minsame,
                           int* __restrict__ wtgt, int B) {
    __shared__ int tg[256];
    __shared__ unsigned char du[256];
    int b = threadIdx.x;
    int t = -1; bool d = false;
    if (b < B) {
        d = maxsim[b] < fmap(0.8f);
        unsigned long long ks = minsame[b];
        unsigned long long ka = minall[b];
        t = (ks != ~0ULL) ? (int)(ks & 0xFFFFFFFFu) : (int)(ka & 0xFFFFFFFFu);
        tg[b] = t; du[b] = d ? 1 : 0;
    }
    __syncthreads();
    if (b < B) {
        bool win = d;
        if (win)
            for (int b2 = b + 1; b2 < B; ++b2)
                if (du[b2] && tg[b2] == t) { win = false; break; }
        wtgt[b] = win ? t : -1;
    }
}

__global__ void copy_keys(const float4* __restrict__ src, float4* __restrict__ dst, long n4) {
    long i = blockIdx.x * (long)blockDim.x + threadIdx.x;
    long stride = (long)gridDim.x * blockDim.x;
    for (; i < n4; i += stride) dst[i] = src[i];
}

__global__ void copy_vals(const int* __restrict__ src, float* __restrict__ dst, int n) {
    int i = blockIdx.x * blockDim.x + threadIdx.x;
    if (i < n) dst[i] = (float)src[i];
}

__global__ void scatter_kernel(const int* __restrict__ wtgt, const float4* __restrict__ upd4,
                               const int* __restrict__ lbl, float4* __restrict__ keys4,
                               float* __restrict__ vals) {
    int b = blockIdx.x;
    int t = wtgt[b];
    if (t < 0) return;
    int l = threadIdx.x; // 64 threads, 64 float4 = 256 floats
    keys4[(long)t * 64 + l] = upd4[(long)b * 64 + l];
    if (l == 0) vals[t] = (float)lbl[b];
}

// ---------- launch ----------

extern "C" void kernel_launch(void* const* d_in, const int* in_sizes, int n_in,
                              void* d_out, int out_size, void* d_ws, size_t ws_size,
                              hipStream_t stream) {
    const float* qf = (const float*)d_in[0];
    const float* mk = (const float*)d_in[1];
    const int*   mv = (const int*)d_in[2];
    const float* uf = (const float*)d_in[3];
    const int*   ul = (const int*)d_in[4];

    const int D = 256;
    const int Q = in_sizes[0] / D;   // 2048
    const int M = in_sizes[2];       // 100000
    const int B = in_sizes[3] / D;   // 128

    float* out = (float*)d_out;
    float* out_keys = out + 2 * (long)Q;
    float* out_vals = out_keys + (long)M * D;

    // workspace carve (256B aligned chunks)
    char* w = (char*)d_ws;
    auto carve = [&](size_t bytes) { char* p = w; w += ((bytes + 255) / 256) * 256; return p; };
    float* rm = (float*)carve((size_t)M * 4);
    float* rq = (float*)carve((size_t)Q * 4);
    float* ru = (float*)carve((size_t)B * 4);
    unsigned long long* packed  = (unsigned long long*)carve((size_t)Q * 8);
    unsigned long long* minall  = (unsigned long long*)carve((size_t)B * 8);
    unsigned long long* minsame = (unsigned long long*)carve((size_t)B * 8);
    unsigned* maxsim = (unsigned*)carve((size_t)B * 4);
    int* wtgt = (int*)carve((size_t)B * 4);

    int initN = (Q > B ? Q : B);
    init_kernel<<<(initN + 255) / 256, 256, 0, stream>>>(packed, maxsim, minall, minsame, Q, B);

    norms_kernel<<<(M + 3) / 4, 256, 0, stream>>>(mk, rm, M);
    norms_kernel<<<(Q + 3) / 4, 256, 0, stream>>>(qf, rq, Q);
    norms_kernel<<<(B + 3) / 4, 256, 0, stream>>>(uf, ru, B);

    dim3 g1((Q + 127) / 128, (M + 127) / 128);
    retrieve_gemm<<<g1, 256, 0, stream>>>(qf, mk, rq, rm, Q, M, packed);

    upd_gemm<<<(M + 127) / 128, 256, 0, stream>>>(uf, mk, ru, rm, mv, ul, B, M,
                                                  maxsim, minall, minsame);

    finish_retrieve<<<(Q + 255) / 256, 256, 0, stream>>>(packed, mv, out, Q);
    finish_upd<<<1, B, 0, stream>>>(maxsim, minall, minsame, wtgt, B);

    copy_keys<<<2048, 256, 0, stream>>>((const float4*)mk, (float4*)out_keys, (long)M * (D / 4));
    copy_vals<<<(M + 255) / 256, 256, 0, stream>>>(mv, out_vals, M);
    scatter_kernel<<<B, 64, 0, stream>>>(wtgt, (const float4*)uf, ul, (float4*)out_keys, out_vals);
}

// Round 2
// 1592.432 us; speedup vs baseline: 2.6038x; 2.6038x over previous
//
#include <hip/hip_runtime.h>

typedef _Float16 half8 __attribute__((ext_vector_type(8)));
typedef float floatx4 __attribute__((ext_vector_type(4)));

// ---------- helpers ----------

__device__ __forceinline__ unsigned fmap(float f) {
    unsigned u = __float_as_uint(f);
    return (u & 0x80000000u) ? ~u : (u | 0x80000000u);
}
__device__ __forceinline__ float funmap(unsigned m) {
    unsigned u = (m & 0x80000000u) ? (m & 0x7FFFFFFFu) : ~m;
    return __uint_as_float(u);
}

__device__ __forceinline__ unsigned long long shfl_xor_u64(unsigned long long v, int mask) {
    unsigned lo = (unsigned)(v & 0xFFFFFFFFu);
    unsigned hi = (unsigned)(v >> 32);
    lo = __shfl_xor(lo, mask, 64);
    hi = __shfl_xor(hi, mask, 64);
    return (((unsigned long long)hi) << 32) | lo;
}

// ---------- small kernels ----------

__global__ void init_kernel(unsigned long long* packed, unsigned* maxsim,
                            unsigned long long* minall, unsigned long long* minsame,
                            int Q, int B) {
    int i = blockIdx.x * blockDim.x + threadIdx.x;
    if (i < Q) packed[i] = 0ULL;
    if (i < B) { maxsim[i] = 0u; minall[i] = ~0ULL; minsame[i] = ~0ULL; }
}

// One wave per row: rn[row] = 1 / max(||X[row,:256]||, 1e-12)
__global__ void norms_kernel(const float* __restrict__ X, float* __restrict__ rn, int rows) {
    int w = (blockIdx.x * blockDim.x + threadIdx.x) >> 6;
    int lane = threadIdx.x & 63;
    if (w >= rows) return;
    float4 v = *(const float4*)&X[(long)w * 256 + lane * 4];
    float s = v.x * v.x + v.y * v.y + v.z * v.z + v.w * v.w;
    #pragma unroll
    for (int o = 32; o >= 1; o >>= 1) s += __shfl_xor(s, o, 64);
    if (lane == 0) rn[w] = 1.0f / fmaxf(sqrtf(s), 1e-12f);
}

// Split normalized rows into fp16 hi/lo, stored in MFMA-fragment order:
// element (q,k) -> idx = ((qt*8+kc)*64 + lane)*8 + j
// qt=q>>4, lane = (q&15) | (((k>>3)&3)<<4), kc=k>>5, j=k&7
__global__ void split_a(const float* __restrict__ X, const float* __restrict__ rn,
                        _Float16* __restrict__ Ah, _Float16* __restrict__ Al, int rows) {
    int e = blockIdx.x * 256 + threadIdx.x;
    if (e >= rows * 256) return;
    int q = e >> 8, k = e & 255;
    float v = X[e] * rn[q];
    _Float16 h = (_Float16)v;
    _Float16 l = (_Float16)((v - (float)h) * 2048.0f);
    int qt = q >> 4, r = q & 15, kc = k >> 5, sub = (k >> 3) & 3, j = k & 7;
    int lane = r | (sub << 4);
    long idx = (((long)(qt * 8 + kc)) * 64 + lane) * 8 + j;
    Ah[idx] = h;
    Al[idx] = l;
}

// ---------- shared device pieces for MFMA GEMMs ----------

union H4 { _Float16 h[4]; uint2 u; };

// Stage a 128-row x 256-col memory tile, normalized + split, into swizzled LDS.
// LDS layout: row-major [col][k] fp16 with byte addr = row*512 + (kbyte ^ ((row&7)<<4))
__device__ __forceinline__ void stage_tile(const float* __restrict__ mk,
                                           const float* __restrict__ rm,
                                           int m0, int M,
                                           _Float16* sBh, _Float16* sBl, int tid) {
    #pragma unroll
    for (int it = 0; it < 16; ++it) {
        int flat4 = it * 512 + tid;       // 8192 float4 = 128 rows x 64 float4
        int row = flat4 >> 6;
        int k4 = (flat4 & 63) << 2;
        int gm = m0 + row;
        float4 f = make_float4(0.f, 0.f, 0.f, 0.f);
        float sc = 0.f;
        if (gm < M) { f = *(const float4*)&mk[(long)gm * 256 + k4]; sc = rm[gm]; }
        float vs0 = f.x * sc, vs1 = f.y * sc, vs2 = f.z * sc, vs3 = f.w * sc;
        H4 hh, ll;
        hh.h[0] = (_Float16)vs0; ll.h[0] = (_Float16)((vs0 - (float)hh.h[0]) * 2048.f);
        hh.h[1] = (_Float16)vs1; ll.h[1] = (_Float16)((vs1 - (float)hh.h[1]) * 2048.f);
        hh.h[2] = (_Float16)vs2; ll.h[2] = (_Float16)((vs2 - (float)hh.h[2]) * 2048.f);
        hh.h[3] = (_Float16)vs3; ll.h[3] = (_Float16)((vs3 - (float)hh.h[3]) * 2048.f);
        int off = row * 512 + (((k4 << 1)) ^ ((row & 7) << 4));
        *(uint2*)((char*)sBh + off) = hh.u;
        *(uint2*)((char*)sBl + off) = ll.u;
    }
    __syncthreads();
}

__device__ __forceinline__ half8 read_frag(const _Float16* sB, int nt, int kc, int lane) {
    int col = (nt << 4) | (lane & 15);
    int kb = ((kc << 5) | ((lane >> 4) << 3)) << 1;  // (kc*32 + (lane>>4)*8) * 2B
    const char* p = (const char*)sB + col * 512 + (kb ^ ((col & 7) << 4));
    return *(const half8*)p;
}

// ---------- retrieve: Q=2048 queries vs 128-col memory tile ----------

__global__ __launch_bounds__(512, 2) void retrieve_mfma(
    const half8* __restrict__ Ah, const half8* __restrict__ Al,
    const float* __restrict__ mk, const float* __restrict__ rm,
    unsigned long long* __restrict__ packed, int M) {
    __shared__ _Float16 sBh[128 * 256];
    __shared__ _Float16 sBl[128 * 256];
    const int tid = threadIdx.x;
    const int m0 = blockIdx.x << 7;
    stage_tile(mk, rm, m0, M, sBh, sBl, tid);

    const int wave = tid >> 6, lane = tid & 63;

    for (int p = 0; p < 8; ++p) {
        const int qt0 = (p * 8 + wave) * 2;   // 2 q-tiles (32 queries) per wave-pass
        half8 ah[2][8], al[2][8];
        #pragma unroll
        for (int t = 0; t < 2; ++t)
            #pragma unroll
            for (int kc = 0; kc < 8; ++kc) {
                long idx = ((long)((qt0 + t) * 8 + kc)) * 64 + lane;
                ah[t][kc] = Ah[idx];
                al[t][kc] = Al[idx];
            }
        unsigned long long best[2][4];
        #pragma unroll
        for (int t = 0; t < 2; ++t)
            #pragma unroll
            for (int r = 0; r < 4; ++r) best[t][r] = 0ULL;

        for (int nt = 0; nt < 8; ++nt) {
            floatx4 accH[2], accM[2];
            #pragma unroll
            for (int t = 0; t < 2; ++t) {
                accH[t] = (floatx4){0.f, 0.f, 0.f, 0.f};
                accM[t] = (floatx4){0.f, 0.f, 0.f, 0.f};
            }
            #pragma unroll
            for (int kc = 0; kc < 8; ++kc) {
                half8 bh = read_frag(sBh, nt, kc, lane);
                half8 bl = read_frag(sBl, nt, kc, lane);
                #pragma unroll
                for (int t = 0; t < 2; ++t) {
                    accH[t] = __builtin_amdgcn_mfma_f32_16x16x32_f16(ah[t][kc], bh, accH[t], 0, 0, 0);
                    accM[t] = __builtin_amdgcn_mfma_f32_16x16x32_f16(ah[t][kc], bl, accM[t], 0, 0, 0);
                    accM[t] = __builtin_amdgcn_mfma_f32_16x16x32_f16(al[t][kc], bh, accM[t], 0, 0, 0);
                }
            }
            int mi = m0 + (nt << 4) + (lane & 15);
            if (mi < M) {
                unsigned lowbits = ~(unsigned)mi;
                #pragma unroll
                for (int t = 0; t < 2; ++t)
                    #pragma unroll
                    for (int r = 0; r < 4; ++r) {
                        float s = accH[t][r] + accM[t][r] * (1.0f / 2048.0f);
                        unsigned long long key =
                            (((unsigned long long)fmap(s)) << 32) | lowbits;
                        if (key > best[t][r]) best[t][r] = key;
                    }
            }
        }
        #pragma unroll
        for (int t = 0; t < 2; ++t)
            #pragma unroll
            for (int r = 0; r < 4; ++r) {
                unsigned long long b = best[t][r];
                #pragma unroll
                for (int o = 1; o < 16; o <<= 1) {
                    unsigned long long ob = shfl_xor_u64(b, o);
                    if (ob > b) b = ob;
                }
                if ((lane & 15) == 0) {
                    int q = (qt0 + t) * 16 + ((lane >> 4) << 2) + r;
                    atomicMax(&packed[q], b);
                }
            }
    }
}

// ---------- update: 128 rows vs 128-col memory tile ----------

__global__ __launch_bounds__(512, 2) void update_mfma(
    const half8* __restrict__ Uh, const half8* __restrict__ Ul,
    const float* __restrict__ mk, const float* __restrict__ rm,
    const int* __restrict__ mv, const int* __restrict__ lbl,
    unsigned* __restrict__ maxsim, unsigned long long* __restrict__ minall,
    unsigned long long* __restrict__ minsame, int M) {
    __shared__ _Float16 sBh[128 * 256];
    __shared__ _Float16 sBl[128 * 256];
    const int tid = threadIdx.x;
    const int m0 = blockIdx.x << 7;
    stage_tile(mk, rm, m0, M, sBh, sBl, tid);

    const int wave = tid >> 6, lane = tid & 63;  // wave = q-tile (rows wave*16..+15)

    half8 ah[8], al[8];
    #pragma unroll
    for (int kc = 0; kc < 8; ++kc) {
        long idx = ((long)(wave * 8 + kc)) * 64 + lane;
        ah[kc] = Uh[idx];
        al[kc] = Ul[idx];
    }
    int lb[4];
    #pragma unroll
    for (int r = 0; r < 4; ++r) lb[r] = lbl[(wave << 4) + ((lane >> 4) << 2) + r];

    unsigned bmax[4];
    unsigned long long ball[4], bsame[4];
    #pragma unroll
    for (int r = 0; r < 4; ++r) { bmax[r] = 0u; ball[r] = ~0ULL; bsame[r] = ~0ULL; }

    for (int nt = 0; nt < 8; ++nt) {
        floatx4 accH = (floatx4){0.f, 0.f, 0.f, 0.f};
        floatx4 accM = (floatx4){0.f, 0.f, 0.f, 0.f};
        #pragma unroll
        for (int kc = 0; kc < 8; ++kc) {
            half8 bh = read_frag(sBh, nt, kc, lane);
            half8 bl = read_frag(sBl, nt, kc, lane);
            accH = __builtin_amdgcn_mfma_f32_16x16x32_f16(ah[kc], bh, accH, 0, 0, 0);
            accM = __builtin_amdgcn_mfma_f32_16x16x32_f16(ah[kc], bl, accM, 0, 0, 0);
            accM = __builtin_amdgcn_mfma_f32_16x16x32_f16(al[kc], bh, accM, 0, 0, 0);
        }
        int mi = m0 + (nt << 4) + (lane & 15);
        if (mi < M) {
            int mvv = mv[mi];
            #pragma unroll
            for (int r = 0; r < 4; ++r) {
                float s = accH[r] + accM[r] * (1.0f / 2048.0f);
                unsigned ms = fmap(s);
                if (ms > bmax[r]) bmax[r] = ms;
                unsigned long long key = (((unsigned long long)ms) << 32) | (unsigned)mi;
                if (key < ball[r]) ball[r] = key;
                if (mvv == lb[r] && key < bsame[r]) bsame[r] = key;
            }
        }
    }
    #pragma unroll
    for (int r = 0; r < 4; ++r) {
        unsigned bm = bmax[r];
        unsigned long long ba = ball[r], bs = bsame[r];
        #pragma unroll
        for (int o = 1; o < 16; o <<= 1) {
            unsigned om = __shfl_xor(bm, o, 64);
            if (om > bm) bm = om;
            unsigned long long oa = shfl_xor_u64(ba, o);
            if (oa < ba) ba = oa;
            unsigned long long os = shfl_xor_u64(bs, o);
            if (os < bs) bs = os;
        }
        if ((lane & 15) == 0) {
            int b = (wave << 4) + ((lane >> 4) << 2) + r;
            atomicMax(&maxsim[b], bm);
            atomicMin(&minall[b], ba);
            atomicMin(&minsame[b], bs);
        }
    }
}

// ---------- finish / output kernels ----------

__global__ void finish_retrieve(const unsigned long long* __restrict__ packed,
                                const int* __restrict__ memvals,
                                float* __restrict__ out, int Q) {
    int q = blockIdx.x * blockDim.x + threadIdx.x;
    if (q >= Q) return;
    unsigned long long key = packed[q];
    unsigned m = ~((unsigned)(key & 0xFFFFFFFFu));
    float conf = funmap((unsigned)(key >> 32));
    out[q] = (float)memvals[m];
    out[Q + q] = conf;
}

__global__ void finish_upd(const unsigned* __restrict__ maxsim,
                           const unsigned long long* __restrict__ minall,
                           const unsigned long long* __restrict__ minsame,
                           int* __restrict__ wtgt, int B) {
    __shared__ int tg[256];
    __shared__ unsigned char du[256];
    int b = threadIdx.x;
    int t = -1; bool d = false;
    if (b < B) {
        d = maxsim[b] < fmap(0.8f);
        unsigned long long ks = minsame[b];
        unsigned long long ka = minall[b];
        t = (ks != ~0ULL) ? (int)(ks & 0xFFFFFFFFu) : (int)(ka & 0xFFFFFFFFu);
        tg[b] = t; du[b] = d ? 1 : 0;
    }
    __syncthreads();
    if (b < B) {
        bool win = d;
        if (win)
            for (int b2 = b + 1; b2 < B; ++b2)
                if (du[b2] && tg[b2] == t) { win = false; break; }
        wtgt[b] = win ? t : -1;
    }
}

__global__ void copy_keys(const float4* __restrict__ src, float4* __restrict__ dst, long n4) {
    long i = blockIdx.x * (long)blockDim.x + threadIdx.x;
    long stride = (long)gridDim.x * blockDim.x;
    for (; i < n4; i += stride) dst[i] = src[i];
}

__global__ void copy_vals(const int* __restrict__ src, float* __restrict__ dst, int n) {
    int i = blockIdx.x * blockDim.x + threadIdx.x;
    if (i < n) dst[i] = (float)src[i];
}

__global__ void scatter_kernel(const int* __restrict__ wtgt, const float4* __restrict__ upd4,
                               const int* __restrict__ lbl, float4* __restrict__ keys4,
                               float* __restrict__ vals) {
    int b = blockIdx.x;
    int t = wtgt[b];
    if (t < 0) return;
    int l = threadIdx.x; // 64 threads x float4 = 256 floats
    keys4[(long)t * 64 + l] = upd4[(long)b * 64 + l];
    if (l == 0) vals[t] = (float)lbl[b];
}

// ---------- launch ----------

extern "C" void kernel_launch(void* const* d_in, const int* in_sizes, int n_in,
                              void* d_out, int out_size, void* d_ws, size_t ws_size,
                              hipStream_t stream) {
    const float* qf = (const float*)d_in[0];
    const float* mk = (const float*)d_in[1];
    const int*   mv = (const int*)d_in[2];
    const float* uf = (const float*)d_in[3];
    const int*   ul = (const int*)d_in[4];

    const int D = 256;
    const int Q = in_sizes[0] / D;   // 2048
    const int M = in_sizes[2];       // 100000
    const int B = in_sizes[3] / D;   // 128

    float* out = (float*)d_out;
    float* out_keys = out + 2 * (long)Q;
    float* out_vals = out_keys + (long)M * D;

    char* w = (char*)d_ws;
    auto carve = [&](size_t bytes) { char* p = w; w += ((bytes + 255) / 256) * 256; return p; };
    float* rm = (float*)carve((size_t)M * 4);
    float* rq = (float*)carve((size_t)Q * 4);
    float* ru = (float*)carve((size_t)B * 4);
    unsigned long long* packed  = (unsigned long long*)carve((size_t)Q * 8);
    unsigned long long* minall  = (unsigned long long*)carve((size_t)B * 8);
    unsigned long long* minsame = (unsigned long long*)carve((size_t)B * 8);
    unsigned* maxsim = (unsigned*)carve((size_t)B * 4);
    int* wtgt = (int*)carve((size_t)B * 4);
    _Float16* Ah = (_Float16*)carve((size_t)Q * D * 2);
    _Float16* Al = (_Float16*)carve((size_t)Q * D * 2);
    _Float16* Uh = (_Float16*)carve((size_t)B * D * 2);
    _Float16* Ul = (_Float16*)carve((size_t)B * D * 2);

    int initN = (Q > B ? Q : B);
    init_kernel<<<(initN + 255) / 256, 256, 0, stream>>>(packed, maxsim, minall, minsame, Q, B);

    norms_kernel<<<(M + 3) / 4, 256, 0, stream>>>(mk, rm, M);
    norms_kernel<<<(Q + 3) / 4, 256, 0, stream>>>(qf, rq, Q);
    norms_kernel<<<(B + 3) / 4, 256, 0, stream>>>(uf, ru, B);

    split_a<<<(Q * D + 255) / 256, 256, 0, stream>>>(qf, rq, Ah, Al, Q);
    split_a<<<(B * D + 255) / 256, 256, 0, stream>>>(uf, ru, Uh, Ul, B);

    int mblocks = (M + 127) / 128;
    retrieve_mfma<<<mblocks, 512, 0, stream>>>((const half8*)Ah, (const half8*)Al,
                                               mk, rm, packed, M);
    update_mfma<<<mblocks, 512, 0, stream>>>((const half8*)Uh, (const half8*)Ul,
                                             mk, rm, mv, ul, maxsim, minall, minsame, M);

    finish_retrieve<<<(Q + 255) / 256, 256, 0, stream>>>(packed, mv, out, Q);
    finish_upd<<<1, B, 0, stream>>>(maxsim, minall, minsame, wtgt, B);

    copy_keys<<<2048, 256, 0, stream>>>((const float4*)mk, (float4*)out_keys, (long)M * (D / 4));
    copy_vals<<<(M + 255) / 256, 256, 0, stream>>>(mv, out_vals, M);
    scatter_kernel<<<B, 64, 0, stream>>>(wtgt, (const float4*)uf, ul, (float4*)out_keys, out_vals);
}